// Round 3
// baseline (1093.484 us; speedup 1.0000x reference)
//
#include <hip/hip_runtime.h>

typedef unsigned short U16;
typedef unsigned int U32;
typedef __bf16 bf16;
typedef bf16 bf16x8 __attribute__((ext_vector_type(8)));
typedef U16  u16x8  __attribute__((ext_vector_type(8)));
typedef float f32x4 __attribute__((ext_vector_type(4)));

// Exact 3-limb bf16 chop split: a == a1 + a2 + a3 (fp32 24-bit significand
// = 3 x 8-bit bf16 limbs; bf16 exponent range == fp32 so no subnormal loss).
__device__ __forceinline__ void split3(float a, U16& o1, U16& o2, U16& o3) {
    U32 ua = __float_as_uint(a);
    float a1 = __uint_as_float(ua & 0xFFFF0000u);
    float r1 = a - a1;
    U32 u2 = __float_as_uint(r1);
    float a2 = __uint_as_float(u2 & 0xFFFF0000u);
    float r2 = r1 - a2;                     // exact in bf16 (<=8 sig bits left)
    o1 = (U16)(ua >> 16);
    o2 = (U16)(u2 >> 16);
    o3 = (U16)(__float_as_uint(r2) >> 16);
}

__device__ __forceinline__ void split3x8(const float v[8], bf16x8& A1, bf16x8& A2, bf16x8& A3) {
    u16x8 e1, e2, e3;
    #pragma unroll
    for (int j = 0; j < 8; ++j) { U16 a, b, c; split3(v[j], a, b, c); e1[j] = a; e2[j] = b; e3[j] = c; }
    A1 = __builtin_bit_cast(bf16x8, e1);
    A2 = __builtin_bit_cast(bf16x8, e2);
    A3 = __builtin_bit_cast(bf16x8, e3);
}

// ---------------- prep: split w1/w2 into bf16 limb planes in d_ws ----------
// w1L: [3][128 n][128 k] bf16 (k 112..127 zero)  = 98304 B at ws+0
// w2L: [3][32 n][128 k]  bf16                    = 24576 B at ws+98304
__global__ __launch_bounds__(256)
void prep_kernel(const float* __restrict__ w1g, const float* __restrict__ w2g,
                 U16* __restrict__ w1L, U16* __restrict__ w2L)
{
    int tid = blockIdx.x * 256 + threadIdx.x;
    if (tid < 2048) {                       // 128 rows x 16 slots of 8 k
        int n = tid >> 4, k0 = (tid & 15) << 3;
        float v[8];
        #pragma unroll
        for (int j = 0; j < 8; ++j) { int k = k0 + j; v[j] = (k < 112) ? w1g[n * 112 + k] : 0.0f; }
        bf16x8 L1, L2, L3; split3x8(v, L1, L2, L3);
        *(bf16x8*)(w1L + 0 * 16384 + n * 128 + k0) = L1;
        *(bf16x8*)(w1L + 1 * 16384 + n * 128 + k0) = L2;
        *(bf16x8*)(w1L + 2 * 16384 + n * 128 + k0) = L3;
    }
    if (tid < 512) {                        // 32 rows x 16 slots
        int n = tid >> 4, k0 = (tid & 15) << 3;
        float v[8];
        #pragma unroll
        for (int j = 0; j < 8; ++j) v[j] = w2g[n * 128 + k0 + j];
        bf16x8 L1, L2, L3; split3x8(v, L1, L2, L3);
        *(bf16x8*)(w2L + 0 * 4096 + n * 128 + k0) = L1;
        *(bf16x8*)(w2L + 1 * 4096 + n * 128 + k0) = L2;
        *(bf16x8*)(w2L + 2 * 4096 + n * 128 + k0) = L3;
    }
}

// ---------------- tap helpers ---------------------------------------------
__device__ __forceinline__ void tap_load(const float* __restrict__ xg, int b, int irow,
                                         int jbase, int j, float v[8])
{
    int tpx = j & 63, cls = j >> 6;
    const float* cbase = xg + (b * 32 + cls) * 16384;
    #pragma unroll
    for (int t = 0; t < 8; ++t) {
        int di = (int)((0x22211000u >> (4 * t)) & 0xFu) - 1;
        int dj = (int)((0x21020210u >> (4 * t)) & 0xFu) - 1;
        int row = irow + di;
        int cc  = jbase + tpx + dj;
        bool okb = ((unsigned)row < 128u) && ((unsigned)cc < 128u);
        int off = okb ? (row * 128 + cc) : 0;      // clamped: always-safe load
        float x = cbase[off];
        v[t] = okb ? x : 0.0f;
    }
}

__device__ __forceinline__ void tap_write(U16* sL, int j, const float v[8])
{
    int tpx = j & 63, cls = j >> 6;
    bf16x8 T1, T2, T3; split3x8(v, T1, T2, T3);
    int to = tpx * 136 + 32 + cls * 8;
    *(bf16x8*)&sL[to] = T1;
    *(bf16x8*)&sL[8704 + to] = T2;
    *(bf16x8*)&sL[17408 + to] = T3;
}

// ---------------- main ----------------------------------------------------
// B=64, C=32, H=W=128. Block = 256 thr = 4 waves = 64 px (one b, row, half).
// WAVE-INDEPENDENT decomposition: after ONE staging barrier, wave wv owns
// pixels wv*16..wv*16+15 end-to-end: stage1 (all 128 h-ch for its 16 px),
// h into its OWN 16 LDS rows (overwriting its own perc rows; wave-local,
// in-order DS, no barrier), stage2, in-register epilogue, wave-local
// store-transpose. Barriers per block: 1 (was 5).
__global__ __launch_bounds__(256, 3)
void cann_kernel(const float* __restrict__ xg,  const U16* __restrict__ w1L,
                 const U16* __restrict__ w2L,
                 const float* __restrict__ b1g, const float* __restrict__ b2g,
                 const float* __restrict__ gg,  const float* __restrict__ bg,
                 float* __restrict__ outg)
{
    __shared__ __align__(16) U16 sL[3 * 8704];        // 52224 B -> 3 blocks/CU

    const int tid  = threadIdx.x;
    const int bid  = blockIdx.x;
    const int jseg = bid & 1;
    const int irow = (bid >> 1) & 127;
    const int b    = bid >> 8;
    const int jbase = jseg << 6;
    const int lane = tid & 63;
    const int wv   = tid >> 6;
    const int quad = lane >> 4;
    const int col  = lane & 15;
    const int px   = tid & 63;
    const int cg   = tid >> 6;

    // ---------------- Phase A: front-load ALL global reads --------------------
    const float* srcA = xg + (b * 32 + cg * 8) * 16384 + irow * 128 + jbase + px;
    float va[8];
    #pragma unroll
    for (int i = 0; i < 8; ++i) va[i] = srcA[i * 16384];   // coalesced

    float vt0[8], vt1[8], vt2[8];                          // 640 tap jobs
    tap_load(xg, b, irow, jbase, tid,       vt0);
    tap_load(xg, b, irow, jbase, tid + 256, vt1);
    if (tid < 128) tap_load(xg, b, irow, jbase, tid + 512, vt2);

    // residual x for this wave's pixels (same lines as center loads -> L1-hot)
    float xs[2][4];
    #pragma unroll
    for (int n2 = 0; n2 < 2; ++n2)
        #pragma unroll
        for (int r = 0; r < 4; ++r)
            xs[n2][r] = xg[(b * 32 + n2 * 16 + col) * 16384 + irow * 128 + jbase
                           + wv * 16 + quad * 4 + r];

    // per-lane params
    float b1f[8];
    #pragma unroll
    for (int nt = 0; nt < 8; ++nt) b1f[nt] = b1g[nt * 16 + col];
    const float b2v0 = b2g[col];
    const float b2v1 = b2g[16 + col];
    float g2v[2], be2v[2];
    g2v[0] = gg[col];      g2v[1] = gg[16 + col];
    be2v[0] = bg[col];     be2v[1] = bg[16 + col];

    // ---------------- split + stage perc into LDS -----------------------------
    {
        bf16x8 L1, L2, L3; split3x8(va, L1, L2, L3);
        int o = px * 136 + cg * 8;
        *(bf16x8*)&sL[o] = L1;
        *(bf16x8*)&sL[8704 + o] = L2;
        *(bf16x8*)&sL[17408 + o] = L3;
    }
    tap_write(sL, tid,       vt0);
    tap_write(sL, tid + 256, vt1);
    if (tid < 128) tap_write(sL, tid + 512, vt2);
    if (tid < 128) {                                      // zero pad k=112..127
        int zo = (tid >> 1) * 136 + 112 + (tid & 1) * 8;
        uint4 z = make_uint4(0u, 0u, 0u, 0u);
        *(uint4*)&sL[zo] = z;
        *(uint4*)&sL[8704 + zo] = z;
        *(uint4*)&sL[17408 + zo] = z;
    }

    // first w1 fragment group issued BEFORE the barrier (vmcnt not drained;
    // survives in flight and lands during the first ds_reads after it)
    bf16x8 pw0, pw1, pw2;
    {
        const U16* wp = w1L + col * 128 + quad * 8;       // nt=0, ks=0
        pw0 = *(const bf16x8*)(wp);
        pw1 = *(const bf16x8*)(wp + 16384);
        pw2 = *(const bf16x8*)(wp + 32768);
    }

    // THE single block barrier: publish perc planes (LDS writes flushed; the
    // global prefetch above is deliberately NOT drained).
    asm volatile("s_waitcnt lgkmcnt(0)" ::: "memory");
    __builtin_amdgcn_s_barrier();
    asm volatile("" ::: "memory");

    // ---------------- Stage 1: h[16 px of this wave][128 ch] -------------------
    // A = perc rows wv*16..+15 (wave-local), B = ALL w1 rows (shared by all
    // waves -> L1/L2-hot). Per-accumulator product order unchanged:
    // ks ascending; A1B1, A1B2, A2B1, A1B3, A2B2, A3B1  -> bit-identical h.
    const f32x4 fz = {0.f, 0.f, 0.f, 0.f};
    f32x4 acc1[8];
    #pragma unroll
    for (int nt = 0; nt < 8; ++nt) acc1[nt] = fz;

    #pragma unroll
    for (int ks = 0; ks < 4; ++ks) {
        // A-fragments for this k-slice (3 ds_read_b128, shared across all nt)
        const int ao = (wv * 16 + col) * 136 + ks * 32 + quad * 8;
        bf16x8 A1 = *(const bf16x8*)&sL[ao];
        bf16x8 A2 = *(const bf16x8*)&sL[8704 + ao];
        bf16x8 A3 = *(const bf16x8*)&sL[17408 + ao];
        #pragma unroll
        for (int nt = 0; nt < 8; ++nt) {
            bf16x8 B1, B2, B3;
            if (ks == 0 && nt == 0) { B1 = pw0; B2 = pw1; B3 = pw2; }
            else {
                const U16* wp = w1L + (nt * 16 + col) * 128 + ks * 32 + quad * 8;
                B1 = *(const bf16x8*)(wp);
                B2 = *(const bf16x8*)(wp + 16384);
                B3 = *(const bf16x8*)(wp + 32768);
            }
            f32x4 a = acc1[nt];
            a = __builtin_amdgcn_mfma_f32_16x16x32_bf16(A1, B1, a, 0, 0, 0);
            a = __builtin_amdgcn_mfma_f32_16x16x32_bf16(A1, B2, a, 0, 0, 0);
            a = __builtin_amdgcn_mfma_f32_16x16x32_bf16(A2, B1, a, 0, 0, 0);
            a = __builtin_amdgcn_mfma_f32_16x16x32_bf16(A1, B3, a, 0, 0, 0);
            a = __builtin_amdgcn_mfma_f32_16x16x32_bf16(A2, B2, a, 0, 0, 0);
            a = __builtin_amdgcn_mfma_f32_16x16x32_bf16(A3, B1, a, 0, 0, 0);
            acc1[nt] = a;
        }
    }

    // ---------------- h -> wave's OWN 16 LDS rows (no barrier) ----------------
    // These rows' perc data was consumed only by THIS wave's A-reads above
    // (data-dependent -> ordered); DS pipe is in-order per wave.
    #pragma unroll
    for (int nt = 0; nt < 8; ++nt) {
        float bb = b1f[nt];
        #pragma unroll
        for (int r = 0; r < 4; ++r) {
            float v = fmaxf(acc1[nt][r] + bb, 0.0f);
            U16 u1, u2, u3; split3(v, u1, u2, u3);
            int ho = (wv * 16 + quad * 4 + r) * 136 + nt * 16 + col;
            sL[ho] = u1; sL[8704 + ho] = u2; sL[17408 + ho] = u3;
        }
    }
    asm volatile("" ::: "memory");   // compiler fence: h-writes before h-reads

    // ---------------- Stage 2: dx = h @ w2^T (wave-local h rows) --------------
    f32x4 acc2[2];
    acc2[0] = fz; acc2[1] = fz;
    #pragma unroll
    for (int ks = 0; ks < 4; ++ks) {
        int k0 = ks * 32 + quad * 8;
        int ho = (wv * 16 + col) * 136 + k0;
        bf16x8 H1 = *(const bf16x8*)&sL[ho];
        bf16x8 H2 = *(const bf16x8*)&sL[8704 + ho];
        bf16x8 H3 = *(const bf16x8*)&sL[17408 + ho];
        #pragma unroll
        for (int n2 = 0; n2 < 2; ++n2) {
            const U16* wp = w2L + (n2 * 16 + col) * 128 + k0;
            bf16x8 B1 = *(const bf16x8*)(wp);
            bf16x8 B2 = *(const bf16x8*)(wp + 4096);
            bf16x8 B3 = *(const bf16x8*)(wp + 8192);
            f32x4 a = acc2[n2];
            a = __builtin_amdgcn_mfma_f32_16x16x32_bf16(H1, B1, a, 0, 0, 0);
            a = __builtin_amdgcn_mfma_f32_16x16x32_bf16(H1, B2, a, 0, 0, 0);
            a = __builtin_amdgcn_mfma_f32_16x16x32_bf16(H2, B1, a, 0, 0, 0);
            a = __builtin_amdgcn_mfma_f32_16x16x32_bf16(H1, B3, a, 0, 0, 0);
            a = __builtin_amdgcn_mfma_f32_16x16x32_bf16(H2, B2, a, 0, 0, 0);
            a = __builtin_amdgcn_mfma_f32_16x16x32_bf16(H3, B1, a, 0, 0, 0);
            acc2[n2] = a;
        }
    }

    // ---------------- Epilogue: in-register mask + LayerNorm (per wave) -------
    // Lane (quad,col) holds pixel p = wv*16+quad*4+r, channels col and 16+col.
    float fin[2][4];
    #pragma unroll
    for (int r = 0; r < 4; ++r) {
        float n0 = acc2[0][r] + b2v0 + xs[0][r];          // ch = col
        float n1 = acc2[1][r] + b2v1 + xs[1][r];          // ch = 16+col
        float cm = (col >= 1 && col <= 9) ? n0 : -3.0e38f;  // classes 1..9
        float z0 = (col == 0)             ? n0 : -3.0e38f;  // class 0
        #pragma unroll
        for (int m = 1; m < 16; m <<= 1) {
            cm = fmaxf(cm, __shfl_xor(cm, m, 64));
            z0 = fmaxf(z0, __shfl_xor(z0, m, 64));
        }
        float keep = (cm > z0) ? 1.0f : 0.0f;             // argmax != 0
        n0 = (col >= 10) ? n0 * keep : n0;                // hidden ch >= 10
        n1 = n1 * keep;                                   // ch 16..31 all hidden
        float s = n0 + n1;
        float q = n0 * n0 + n1 * n1;
        #pragma unroll
        for (int m = 1; m < 16; m <<= 1) {
            s += __shfl_xor(s, m, 64);
            q += __shfl_xor(q, m, 64);
        }
        float mu  = s * 0.03125f;
        float var = q * 0.03125f - mu * mu;
        float rstd = 1.0f / sqrtf(var + 1e-5f);
        fin[0][r] = (n0 - mu) * rstd * g2v[0] + be2v[0];
        fin[1][r] = (n1 - mu) * rstd * g2v[1] + be2v[1];
    }

    // ---------------- wave-local store transpose (no barrier) -----------------
    // Scratch = this wave's OWN plane-0 rows (byte offset wv*4352, need 2112 B).
    // Stage-2 H-reads of these rows completed (data-dependent via acc2/fin).
    asm volatile("" ::: "memory");
    float* dxs = (float*)(sL + wv * 2176);                // wv*4352 bytes
    #pragma unroll
    for (int n2 = 0; n2 < 2; ++n2)
        #pragma unroll
        for (int r = 0; r < 4; ++r) {
            int p = quad * 4 + r;                         // 0..15 (wave-local)
            dxs[p * 33 + n2 * 16 + col] = fin[n2][r];
        }
    asm volatile("" ::: "memory");   // compiler fence: writes before reads

    // coalesced store: iteration i -> 4 channels x 16 px (4 full 64B lines)
    {
        int cq   = lane >> 4;                             // channel sub-index
        int pcol = lane & 15;                             // pixel within wave
        int base = b * 524288 + irow * 128 + jbase + wv * 16 + pcol;
        #pragma unroll
        for (int i = 0; i < 8; ++i) {
            int ch = i * 4 + cq;
            outg[base + ch * 16384] = dxs[pcol * 33 + ch];
        }
    }
}

extern "C" void kernel_launch(void* const* d_in, const int* in_sizes, int n_in,
                              void* d_out, int out_size, void* d_ws, size_t ws_size,
                              hipStream_t stream) {
    const float* x  = (const float*)d_in[0];
    const float* w1 = (const float*)d_in[1];
    const float* b1 = (const float*)d_in[2];
    const float* w2 = (const float*)d_in[3];
    const float* b2 = (const float*)d_in[4];
    const float* g  = (const float*)d_in[5];
    const float* be = (const float*)d_in[6];
    float* out = (float*)d_out;

    U16* w1L = (U16*)d_ws;                       // 98304 B
    U16* w2L = (U16*)((char*)d_ws + 98304);      // 24576 B (total 122880 <= ws)

    hipLaunchKernelGGL(prep_kernel, dim3(8), dim3(256), 0, stream, w1, w2, w1L, w2L);
    // grid: 64 (B) * 128 (rows) * 2 (W/64) = 16384 blocks
    hipLaunchKernelGGL(cann_kernel, dim3(16384), dim3(256), 0, stream,
                       x, w1L, w2L, b1, b2, g, be, out);
}

// Round 4
// 577.972 us; speedup vs baseline: 1.8919x; 1.8919x over previous
//
#include <hip/hip_runtime.h>

typedef unsigned short U16;
typedef unsigned int U32;
typedef __bf16 bf16;
typedef bf16 bf16x8 __attribute__((ext_vector_type(8)));
typedef U16  u16x8  __attribute__((ext_vector_type(8)));
typedef float f32x4 __attribute__((ext_vector_type(4)));

// Exact 3-limb bf16 chop split: a == a1 + a2 + a3 (fp32 24-bit significand
// = 3 x 8-bit bf16 limbs; bf16 exponent range == fp32 so no subnormal loss).
__device__ __forceinline__ void split3(float a, U16& o1, U16& o2, U16& o3) {
    U32 ua = __float_as_uint(a);
    float a1 = __uint_as_float(ua & 0xFFFF0000u);
    float r1 = a - a1;
    U32 u2 = __float_as_uint(r1);
    float a2 = __uint_as_float(u2 & 0xFFFF0000u);
    float r2 = r1 - a2;                     // exact in bf16 (<=8 sig bits left)
    o1 = (U16)(ua >> 16);
    o2 = (U16)(u2 >> 16);
    o3 = (U16)(__float_as_uint(r2) >> 16);
}

__device__ __forceinline__ void split3x8(const float v[8], bf16x8& A1, bf16x8& A2, bf16x8& A3) {
    u16x8 e1, e2, e3;
    #pragma unroll
    for (int j = 0; j < 8; ++j) { U16 a, b, c; split3(v[j], a, b, c); e1[j] = a; e2[j] = b; e3[j] = c; }
    A1 = __builtin_bit_cast(bf16x8, e1);
    A2 = __builtin_bit_cast(bf16x8, e2);
    A3 = __builtin_bit_cast(bf16x8, e3);
}

// ---------------- prep: split w1/w2 into bf16 limb planes in d_ws ----------
// w1L: [3][128 n][128 k] bf16 (k 112..127 zero)  = 98304 B at ws+0
// w2L: [3][32 n][128 k]  bf16                    = 24576 B at ws+98304
__global__ __launch_bounds__(256)
void prep_kernel(const float* __restrict__ w1g, const float* __restrict__ w2g,
                 U16* __restrict__ w1L, U16* __restrict__ w2L)
{
    int tid = blockIdx.x * 256 + threadIdx.x;
    if (tid < 2048) {                       // 128 rows x 16 slots of 8 k
        int n = tid >> 4, k0 = (tid & 15) << 3;
        float v[8];
        #pragma unroll
        for (int j = 0; j < 8; ++j) { int k = k0 + j; v[j] = (k < 112) ? w1g[n * 112 + k] : 0.0f; }
        bf16x8 L1, L2, L3; split3x8(v, L1, L2, L3);
        *(bf16x8*)(w1L + 0 * 16384 + n * 128 + k0) = L1;
        *(bf16x8*)(w1L + 1 * 16384 + n * 128 + k0) = L2;
        *(bf16x8*)(w1L + 2 * 16384 + n * 128 + k0) = L3;
    }
    if (tid < 512) {                        // 32 rows x 16 slots
        int n = tid >> 4, k0 = (tid & 15) << 3;
        float v[8];
        #pragma unroll
        for (int j = 0; j < 8; ++j) v[j] = w2g[n * 128 + k0 + j];
        bf16x8 L1, L2, L3; split3x8(v, L1, L2, L3);
        *(bf16x8*)(w2L + 0 * 4096 + n * 128 + k0) = L1;
        *(bf16x8*)(w2L + 1 * 4096 + n * 128 + k0) = L2;
        *(bf16x8*)(w2L + 2 * 4096 + n * 128 + k0) = L3;
    }
}

// ---------------- barrier macros (NO vmcnt drain — keep loads in flight) ---
#define WBAR() do { asm volatile("s_waitcnt lgkmcnt(0)" ::: "memory"); \
                    __builtin_amdgcn_s_barrier();                      \
                    asm volatile("" ::: "memory"); } while (0)
#define RBAR() do { asm volatile("" ::: "memory");                     \
                    __builtin_amdgcn_s_barrier();                      \
                    asm volatile("" ::: "memory"); } while (0)

// ---------------- tap helpers ---------------------------------------------
__device__ __forceinline__ void tap_load(const float* __restrict__ xg, int b, int irow,
                                         int jbase, int j, float v[8])
{
    int tpx = j & 63, cls = j >> 6;
    const float* cbase = xg + (b * 32 + cls) * 16384;
    #pragma unroll
    for (int t = 0; t < 8; ++t) {
        int di = (int)((0x22211000u >> (4 * t)) & 0xFu) - 1;
        int dj = (int)((0x21020210u >> (4 * t)) & 0xFu) - 1;
        int row = irow + di;
        int cc  = jbase + tpx + dj;
        bool okb = ((unsigned)row < 128u) && ((unsigned)cc < 128u);
        int off = okb ? (row * 128 + cc) : 0;      // clamped: always-safe load
        float x = cbase[off];
        v[t] = okb ? x : 0.0f;
    }
}

__device__ __forceinline__ void tap_write(U16* sL, int j, const float v[8])
{
    int tpx = j & 63, cls = j >> 6;
    bf16x8 T1, T2, T3; split3x8(v, T1, T2, T3);
    int to = tpx * 136 + 32 + cls * 8;
    *(bf16x8*)&sL[to] = T1;
    *(bf16x8*)&sL[8704 + to] = T2;
    *(bf16x8*)&sL[17408 + to] = T3;
}

// ---- stage-1 helpers: w1 fragment group load + one ks MFMA cluster --------
// frag(L,n2) at w1p + L*16384 + n2*2048 + ks*32  (w1p = row wv*32+col, quad*8)
#define LDW1(g, ks_) do {                                                    \
    _Pragma("unroll") for (int L_ = 0; L_ < 3; ++L_)                         \
    _Pragma("unroll") for (int n_ = 0; n_ < 2; ++n_)                         \
        g[L_ * 2 + n_] = *(const bf16x8*)(w1p + L_ * 16384 + n_ * 2048 + (ks_) * 32); \
} while (0)

#define MFMA1(ks_, g) do {                                                   \
    _Pragma("unroll") for (int mt_ = 0; mt_ < 4; ++mt_) {                    \
        const int ao_ = (mt_ * 16 + col) * 136 + (ks_) * 32 + quad * 8;      \
        bf16x8 A1_ = *(const bf16x8*)&sL[ao_];                               \
        bf16x8 A2_ = *(const bf16x8*)&sL[8704 + ao_];                        \
        bf16x8 A3_ = *(const bf16x8*)&sL[17408 + ao_];                       \
        _Pragma("unroll") for (int n_ = 0; n_ < 2; ++n_) {                   \
            f32x4 a_ = acc1[mt_][n_];                                        \
            a_ = __builtin_amdgcn_mfma_f32_16x16x32_bf16(A1_, g[0 + n_], a_, 0, 0, 0); \
            a_ = __builtin_amdgcn_mfma_f32_16x16x32_bf16(A1_, g[2 + n_], a_, 0, 0, 0); \
            a_ = __builtin_amdgcn_mfma_f32_16x16x32_bf16(A2_, g[0 + n_], a_, 0, 0, 0); \
            a_ = __builtin_amdgcn_mfma_f32_16x16x32_bf16(A1_, g[4 + n_], a_, 0, 0, 0); \
            a_ = __builtin_amdgcn_mfma_f32_16x16x32_bf16(A2_, g[2 + n_], a_, 0, 0, 0); \
            a_ = __builtin_amdgcn_mfma_f32_16x16x32_bf16(A3_, g[0 + n_], a_, 0, 0, 0); \
            acc1[mt_][n_] = a_;                                              \
        }                                                                    \
    }                                                                        \
} while (0)

// ---- stage-2 helpers ------------------------------------------------------
#define LDW2(q, ks_) do {                                                    \
    _Pragma("unroll") for (int L_ = 0; L_ < 3; ++L_)                         \
    _Pragma("unroll") for (int n_ = 0; n_ < 2; ++n_)                         \
        q[L_ * 2 + n_] = *(const bf16x8*)(w2p + L_ * 4096 + n_ * 2048 + (ks_) * 32); \
} while (0)

#define MFMA2(ks_, q) do {                                                   \
    const int ho_ = (wv * 16 + col) * 136 + (ks_) * 32 + quad * 8;           \
    bf16x8 H1_ = *(const bf16x8*)&sL[ho_];                                   \
    bf16x8 H2_ = *(const bf16x8*)&sL[8704 + ho_];                            \
    bf16x8 H3_ = *(const bf16x8*)&sL[17408 + ho_];                           \
    _Pragma("unroll") for (int n_ = 0; n_ < 2; ++n_) {                       \
        f32x4 a_ = acc2[n_];                                                 \
        a_ = __builtin_amdgcn_mfma_f32_16x16x32_bf16(H1_, q[0 + n_], a_, 0, 0, 0); \
        a_ = __builtin_amdgcn_mfma_f32_16x16x32_bf16(H1_, q[2 + n_], a_, 0, 0, 0); \
        a_ = __builtin_amdgcn_mfma_f32_16x16x32_bf16(H2_, q[0 + n_], a_, 0, 0, 0); \
        a_ = __builtin_amdgcn_mfma_f32_16x16x32_bf16(H1_, q[4 + n_], a_, 0, 0, 0); \
        a_ = __builtin_amdgcn_mfma_f32_16x16x32_bf16(H2_, q[2 + n_], a_, 0, 0, 0); \
        a_ = __builtin_amdgcn_mfma_f32_16x16x32_bf16(H3_, q[0 + n_], a_, 0, 0, 0); \
        acc2[n_] = a_;                                                       \
    }                                                                        \
} while (0)

// ---------------- main ----------------------------------------------------
// r0 structure (n-split stage 1, m-split stage 2, 5-phase, 16384 blocks) with:
//  - ks-outer stage loops + 4 named operand groups (each fragment loaded once,
//    its 4 uses adjacent) + sched_group_barrier VMEM anchors (issue one MFMA
//    cluster ahead of use)
//  - raw s_barrier (lgkmcnt-only) so prefetches survive barriers
//  - XCD-contiguous block swizzle (FETCH 137->66 MB proven in r1)
__global__ __launch_bounds__(256, 3)
void cann_kernel(const float* __restrict__ xg,  const U16* __restrict__ w1L,
                 const U16* __restrict__ w2L,
                 const float* __restrict__ b1g, const float* __restrict__ b2g,
                 const float* __restrict__ gg,  const float* __restrict__ bg,
                 float* __restrict__ outg)
{
    __shared__ __align__(16) U16 sL[3 * 8704];        // 52224 B -> 3 blocks/CU

    const int tid  = threadIdx.x;
    const int bid0 = blockIdx.x;
    const int bid  = (bid0 & 7) * 2048 + (bid0 >> 3);  // XCD-contiguous, bijective
    const int jseg = bid & 1;
    const int irow = (bid >> 1) & 127;
    const int b    = bid >> 8;
    const int jbase = jseg << 6;
    const int lane = tid & 63;
    const int wv   = tid >> 6;
    const int quad = lane >> 4;
    const int col  = lane & 15;
    const int px   = tid & 63;
    const int cg   = tid >> 6;

    const U16* w1p = w1L + (wv * 32 + col) * 128 + quad * 8;
    const U16* w2p = w2L + col * 128 + quad * 8;

    // ---------------- Phase A: stage perc as 3 bf16 limb planes ---------------
    {
        // (a) channels 0..31: one thread = one pixel x 8 channels
        const float* src = xg + (b * 32 + cg * 8) * 16384 + irow * 128 + jbase + px;
        float va[8];
        #pragma unroll
        for (int i = 0; i < 8; ++i) va[i] = src[i * 16384];   // coalesced
        bf16x8 L1, L2, L3; split3x8(va, L1, L2, L3);
        int o = px * 136 + cg * 8;
        *(bf16x8*)&sL[o] = L1;
        *(bf16x8*)&sL[8704 + o] = L2;
        *(bf16x8*)&sL[17408 + o] = L3;
    }
    {
        float vt[8];
        tap_load(xg, b, irow, jbase, tid, vt);       tap_write(sL, tid, vt);
        tap_load(xg, b, irow, jbase, tid + 256, vt); tap_write(sL, tid + 256, vt);
        if (tid < 128) { tap_load(xg, b, irow, jbase, tid + 512, vt);
                         tap_write(sL, tid + 512, vt); }
    }
    if (tid < 128) {                                  // zero pad k=112..127
        int zo = (tid >> 1) * 136 + 112 + (tid & 1) * 8;
        uint4 z = make_uint4(0u, 0u, 0u, 0u);
        *(uint4*)&sL[zo] = z;
        *(uint4*)&sL[8704 + zo] = z;
        *(uint4*)&sL[17408 + zo] = z;
    }

    // per-lane params + residual (same lines as center loads -> L1/L2-hot)
    const float b1v0 = b1g[wv * 32 + col];
    const float b1v1 = b1g[wv * 32 + 16 + col];
    const float b2v0 = b2g[col];
    const float b2v1 = b2g[16 + col];
    float xs[2][4];
    #pragma unroll
    for (int n2 = 0; n2 < 2; ++n2)
        #pragma unroll
        for (int r = 0; r < 4; ++r)
            xs[n2][r] = xg[(b * 32 + n2 * 16 + col) * 16384 + irow * 128 + jbase
                           + wv * 16 + quad * 4 + r];

    // stage-1 operand groups for ks=0,1 issued pre-barrier (survive raw barrier)
    bf16x8 g0[6], g1[6], g2[6], g3[6];
    LDW1(g0, 0);
    LDW1(g1, 1);

    WBAR();   // B1: perc planes published (global prefetches NOT drained)

    // ---------------- Stage 1: h = relu(perc @ w1^T + b1), split-N ------------
    const f32x4 fz = {0.f, 0.f, 0.f, 0.f};
    f32x4 acc1[4][2];
    #pragma unroll
    for (int mt = 0; mt < 4; ++mt) { acc1[mt][0] = fz; acc1[mt][1] = fz; }

    LDW1(g2, 2);
    __builtin_amdgcn_sched_group_barrier(0x20, 6, 0);   // g2 issues here
    MFMA1(0, g0);
    LDW1(g3, 3);
    __builtin_amdgcn_sched_group_barrier(0x20, 6, 0);   // g3 issues here
    MFMA1(1, g1);
    MFMA1(2, g2);
    MFMA1(3, g3);

    RBAR();   // B2: all perc reads consumed -> planes reusable for h

    // stage-2 operand groups for ks=0,1: issue now, latency hides under h-split
    bf16x8 q0[6], q1[6], q2[6], q3[6];
    LDW2(q0, 0);
    LDW2(q1, 1);
    __builtin_amdgcn_sched_group_barrier(0x20, 12, 0);  // q0,q1 issue here

    // h -> 3 limb planes (exact split of relu(acc+b1))
    #pragma unroll
    for (int mt = 0; mt < 4; ++mt)
        #pragma unroll
        for (int n2 = 0; n2 < 2; ++n2) {
            float bb = n2 ? b1v1 : b1v0;
            #pragma unroll
            for (int r = 0; r < 4; ++r) {
                float v = fmaxf(acc1[mt][n2][r] + bb, 0.0f);
                U16 u1, u2, u3; split3(v, u1, u2, u3);
                int ho = (mt * 16 + quad * 4 + r) * 136 + wv * 32 + n2 * 16 + col;
                sL[ho] = u1; sL[8704 + ho] = u2; sL[17408 + ho] = u3;
            }
        }

    WBAR();   // B3: h planes published (q0/q1 prefetches NOT drained)

    // ---------------- Stage 2: dx = h @ w2^T, waves split-M -------------------
    f32x4 acc2[2];
    acc2[0] = fz; acc2[1] = fz;

    LDW2(q2, 2);
    __builtin_amdgcn_sched_group_barrier(0x20, 6, 0);   // q2 issues here
    MFMA2(0, q0);
    LDW2(q3, 3);
    __builtin_amdgcn_sched_group_barrier(0x20, 6, 0);   // q3 issues here
    MFMA2(1, q1);
    MFMA2(2, q2);
    MFMA2(3, q3);

    RBAR();   // B4a: stage-2 h reads consumed -> plane mem reusable (dxl)

    // new_state = x + dx + b2 -> dxl f32 [64][33]
    float* dxl = (float*)sL;
    #pragma unroll
    for (int n2 = 0; n2 < 2; ++n2) {
        float bb = n2 ? b2v1 : b2v0;
        int c = n2 * 16 + col;
        #pragma unroll
        for (int r = 0; r < 4; ++r) {
            int p = wv * 16 + quad * 4 + r;
            dxl[p * 33 + c] = acc2[n2][r] + bb + xs[n2][r];
        }
    }

    WBAR();   // B4: new_state complete

    // ---------------- Epilogue: mask + LayerNorm + fp32 store (wave 0) --------
    if (tid < 64) {
        int p = tid;
        float ns[32];
        #pragma unroll
        for (int c = 0; c < 32; ++c) ns[c] = dxl[p * 33 + c];
        // argmax over classes 0..9 (ties -> first). keep hidden iff argmax != 0
        float m = ns[1];
        #pragma unroll
        for (int c = 2; c < 10; ++c) m = fmaxf(m, ns[c]);
        float keep = (m > ns[0]) ? 1.0f : 0.0f;
        #pragma unroll
        for (int c = 10; c < 32; ++c) ns[c] *= keep;
        float s = 0.f;
        #pragma unroll
        for (int c = 0; c < 32; ++c) s += ns[c];
        float mu = s * 0.03125f;
        float var = 0.f;
        #pragma unroll
        for (int c = 0; c < 32; ++c) { float d = ns[c] - mu; var += d * d; }
        var *= 0.03125f;
        float rstd = 1.0f / sqrtf(var + 1e-5f);
        int base = b * 524288 + irow * 128 + jbase + p;
        #pragma unroll
        for (int c = 0; c < 32; ++c)
            outg[base + c * 16384] = (ns[c] - mu) * rstd * gg[c] + bg[c];  // coalesced
    }
}

extern "C" void kernel_launch(void* const* d_in, const int* in_sizes, int n_in,
                              void* d_out, int out_size, void* d_ws, size_t ws_size,
                              hipStream_t stream) {
    const float* x  = (const float*)d_in[0];
    const float* w1 = (const float*)d_in[1];
    const float* b1 = (const float*)d_in[2];
    const float* w2 = (const float*)d_in[3];
    const float* b2 = (const float*)d_in[4];
    const float* g  = (const float*)d_in[5];
    const float* be = (const float*)d_in[6];
    float* out = (float*)d_out;

    U16* w1L = (U16*)d_ws;                       // 98304 B
    U16* w2L = (U16*)((char*)d_ws + 98304);      // 24576 B (total 122880 <= ws)

    hipLaunchKernelGGL(prep_kernel, dim3(8), dim3(256), 0, stream, w1, w2, w1L, w2L);
    // grid: 64 (B) * 128 (rows) * 2 (W/64) = 16384 blocks
    hipLaunchKernelGGL(cann_kernel, dim3(16384), dim3(256), 0, stream,
                       x, w1L, w2L, b1, b2, g, be, out);
}